// Round 1
// baseline (996.894 us; speedup 1.0000x reference)
//
#include <hip/hip_runtime.h>

#define N_NODES 50000

// One wave (64 lanes) per edge: lane f handles feature f.
// Gather h[src] (coalesced 256B) and atomically accumulate into agg[dst].
// Lane 0 optionally bumps the in-degree count.
__global__ __launch_bounds__(256) void scatter_kernel(
    const int* __restrict__ src, const int* __restrict__ dst,
    const float* __restrict__ h, float* __restrict__ agg,
    float* __restrict__ cnt, int E, int do_cnt)
{
    int total = E * 64;
    int stride = gridDim.x * blockDim.x;
    for (int t = blockIdx.x * blockDim.x + threadIdx.x; t < total; t += stride) {
        int e = t >> 6;
        int f = t & 63;
        int s = src[e];
        int d = dst[e];
        float v = h[(size_t)s * 64 + f];
        atomicAdd(&agg[(size_t)d * 64 + f], v);
        if (do_cnt && f == 0) atomicAdd(&cnt[d], 1.0f);
    }
}

// Fused per-layer GEMM:
//   hout[i,:] = relu( (agg0[i,:]/max(cnt0,1)) @ Wl0
//                   + (agg1[i,:]/max(cnt1,1)) @ Wl1
//                   + h[i,:] @ (Wr0 + Wr1)
//                   + (b0 + b1) )
// Concatenated-K (192) GEMM with all weights staged in LDS.
// Block = 256 threads = 4 nodes x 64 output features; wave-uniform node ->
// rows[nl][k] reads are LDS broadcasts, Wc[k*64+j] reads are 2-way (free).
__global__ __launch_bounds__(256) void layer_gemm(
    const float* __restrict__ agg0, const float* __restrict__ cnt0,
    const float* __restrict__ agg1, const float* __restrict__ cnt1,
    const float* __restrict__ h,
    const float* __restrict__ Wl0, const float* __restrict__ Wl1,
    const float* __restrict__ Wr0, const float* __restrict__ Wr1,
    const float* __restrict__ b0, const float* __restrict__ b1,
    float* __restrict__ hout)
{
    __shared__ float Wc[192 * 64];    // rows 0-63: Wl0, 64-127: Wl1, 128-191: Wr0+Wr1
    __shared__ float bias[64];
    __shared__ float rows[4][192];

    int tid = threadIdx.x;
    for (int i = tid; i < 4096; i += 256) {
        Wc[i]        = Wl0[i];
        Wc[4096 + i] = Wl1[i];
        Wc[8192 + i] = Wr0[i] + Wr1[i];
    }
    if (tid < 64) bias[tid] = b0[tid] + b1[tid];

    int j = tid & 63;
    int nl = tid >> 6;

    for (int base = blockIdx.x * 4; base < N_NODES; base += gridDim.x * 4) {
        __syncthreads();  // covers weight load (1st iter) + rows reuse (later iters)
        // Stage 4 nodes x 192 concatenated features into LDS
        for (int i = tid; i < 768; i += 256) {
            int n = i / 192, k = i % 192;
            int node = base + n;
            float v = 0.0f;
            if (node < N_NODES) {
                if (k < 64) {
                    float c = cnt0[node];
                    v = agg0[(size_t)node * 64 + k] / fmaxf(c, 1.0f);
                } else if (k < 128) {
                    float c = cnt1[node];
                    v = agg1[(size_t)node * 64 + (k - 64)] / fmaxf(c, 1.0f);
                } else {
                    v = h[(size_t)node * 64 + (k - 128)];
                }
            }
            rows[n][k] = v;
        }
        __syncthreads();

        int node = base + nl;
        if (node < N_NODES) {
            float acc = bias[j];
            #pragma unroll
            for (int k = 0; k < 192; k += 4) {
                float4 rv = *(const float4*)&rows[nl][k];
                acc = fmaf(rv.x, Wc[(k + 0) * 64 + j], acc);
                acc = fmaf(rv.y, Wc[(k + 1) * 64 + j], acc);
                acc = fmaf(rv.z, Wc[(k + 2) * 64 + j], acc);
                acc = fmaf(rv.w, Wc[(k + 3) * 64 + j], acc);
            }
            hout[(size_t)node * 64 + j] = fmaxf(acc, 0.0f);
        }
    }
}

// Final projection: out[i,:32] = h[i,:64] @ W + b
__global__ __launch_bounds__(256) void final_gemm(
    const float* __restrict__ h, const float* __restrict__ W,
    const float* __restrict__ b, float* __restrict__ out)
{
    __shared__ float Ws[64 * 32];
    __shared__ float bs[32];
    __shared__ float rows[8][64];

    int tid = threadIdx.x;
    for (int i = tid; i < 2048; i += 256) Ws[i] = W[i];
    if (tid < 32) bs[tid] = b[tid];

    int j = tid & 31;
    int nl = tid >> 5;  // 8 nodes per block-iteration

    for (int base = blockIdx.x * 8; base < N_NODES; base += gridDim.x * 8) {
        __syncthreads();
        for (int i = tid; i < 512; i += 256) {
            int n = i >> 6, k = i & 63;
            int node = base + n;
            rows[n][k] = (node < N_NODES) ? h[(size_t)node * 64 + k] : 0.0f;
        }
        __syncthreads();

        int node = base + nl;
        if (node < N_NODES) {
            float acc = bs[j];
            #pragma unroll
            for (int k = 0; k < 64; k += 4) {
                float4 rv = *(const float4*)&rows[nl][k];
                acc = fmaf(rv.x, Ws[(k + 0) * 32 + j], acc);
                acc = fmaf(rv.y, Ws[(k + 1) * 32 + j], acc);
                acc = fmaf(rv.z, Ws[(k + 2) * 32 + j], acc);
                acc = fmaf(rv.w, Ws[(k + 3) * 32 + j], acc);
            }
            out[(size_t)node * 32 + j] = acc;
        }
    }
}

extern "C" void kernel_launch(void* const* d_in, const int* in_sizes, int n_in,
                              void* d_out, int out_size, void* d_ws, size_t ws_size,
                              hipStream_t stream)
{
    const float* x    = (const float*)d_in[0];
    const int*   ei0  = (const int*)d_in[1];
    const int*   ei1  = (const int*)d_in[2];
    const float* Wl   = (const float*)d_in[3];   // [2,2,64,64]
    const float* Wr   = (const float*)d_in[4];   // [2,2,64,64]
    const float* bl   = (const float*)d_in[5];   // [2,2,64]
    const float* linW = (const float*)d_in[6];   // [64,32]
    const float* linb = (const float*)d_in[7];   // [32]
    float* out = (float*)d_out;

    int E0 = in_sizes[1] / 2;
    int E1 = in_sizes[2] / 2;

    // Workspace layout (contiguous so agg+cnt zero in one memset):
    // [agg0 12.8MB | agg1 12.8MB | cnt0 200KB | cnt1 200KB | h1 12.8MB | h2 12.8MB]
    float* agg0 = (float*)d_ws;
    float* agg1 = agg0 + (size_t)N_NODES * 64;
    float* cnt0 = agg1 + (size_t)N_NODES * 64;
    float* cnt1 = cnt0 + N_NODES;
    float* h1   = cnt1 + N_NODES;
    float* h2   = h1 + (size_t)N_NODES * 64;

    size_t agg_bytes = (size_t)N_NODES * 64 * 2 * sizeof(float);
    size_t cnt_bytes = (size_t)N_NODES * 2 * sizeof(float);

    dim3 blk(256);
    dim3 sgrid(8192);   // grid-stride over E*64 work items
    dim3 ggrid(768);    // 3 blocks/CU resident (52.5KB LDS) x 256 CU

    // ---- Layer 0 (input x) ----
    hipMemsetAsync(agg0, 0, agg_bytes + cnt_bytes, stream);
    scatter_kernel<<<sgrid, blk, 0, stream>>>(ei0, ei0 + E0, x, agg0, cnt0, E0, 1);
    scatter_kernel<<<sgrid, blk, 0, stream>>>(ei1, ei1 + E1, x, agg1, cnt1, E1, 1);
    layer_gemm<<<ggrid, blk, 0, stream>>>(agg0, cnt0, agg1, cnt1, x,
        Wl + 0, Wl + 4096, Wr + 0, Wr + 4096, bl + 0, bl + 64, h1);

    // ---- Layer 1 (input h1; counts are identical, skip recompute) ----
    hipMemsetAsync(agg0, 0, agg_bytes, stream);
    scatter_kernel<<<sgrid, blk, 0, stream>>>(ei0, ei0 + E0, h1, agg0, cnt0, E0, 0);
    scatter_kernel<<<sgrid, blk, 0, stream>>>(ei1, ei1 + E1, h1, agg1, cnt1, E1, 0);
    layer_gemm<<<ggrid, blk, 0, stream>>>(agg0, cnt0, agg1, cnt1, h1,
        Wl + 8192, Wl + 12288, Wr + 8192, Wr + 12288, bl + 128, bl + 192, h2);

    // ---- Final projection ----
    final_gemm<<<ggrid, blk, 0, stream>>>(h2, linW, linb, out);
}

// Round 3
// 465.953 us; speedup vs baseline: 2.1395x; 2.1395x over previous
//
#include <hip/hip_runtime.h>

#define NN 50000
#define CAP 32          // per-node bin capacity; overflow handled correctly
#define OVF_CAP 4096

// Single pass over both relations: rank = atomicAdd(deg), write src into the
// node's bin. Rare overflow (deg > CAP) goes to a list, fixed up later.
__global__ __launch_bounds__(256) void bin_fill(
    const int* __restrict__ ei0, int E0,
    const int* __restrict__ ei1, int E1,
    int* __restrict__ deg,       // [2*NN]
    int* __restrict__ bins,      // [2*NN][CAP]
    int2* __restrict__ ovf, int* __restrict__ ovf_cnt)
{
    int total = E0 + E1;
    int stride = gridDim.x * blockDim.x;
    for (int t = blockIdx.x * blockDim.x + threadIdx.x; t < total; t += stride) {
        int s, node;
        if (t < E0) { s = ei0[t]; node = ei0[E0 + t]; }
        else        { int u = t - E0; s = ei1[u]; node = NN + ei1[E1 + u]; }
        int r = atomicAdd(&deg[node], 1);
        if (r < CAP) {
            bins[(size_t)node * CAP + r] = s;
        } else {
            int o = atomicAdd(ovf_cnt, 1);
            if (o < OVF_CAP) ovf[o] = make_int2(node, s);
        }
    }
}

// One wave per (relation,node): coalesced bin read, shfl-broadcast indices,
// 4 independent gather-accumulate chains, write mean.
__global__ __launch_bounds__(256) void aggregate(
    const int* __restrict__ bins, const int* __restrict__ deg,
    const float* __restrict__ h, float* __restrict__ agg)
{
    int lane = threadIdx.x & 63;
    int wid = (blockIdx.x * blockDim.x + threadIdx.x) >> 6;
    int nwaves = (gridDim.x * blockDim.x) >> 6;
    for (int task = wid; task < 2 * NN; task += nwaves) {
        int d = deg[task];
        int m = min(d, CAP);
        int idx = 0;
        if (lane < m) idx = bins[(size_t)task * CAP + lane];
        float a0 = 0.f, a1 = 0.f, a2 = 0.f, a3 = 0.f;
        int t = 0;
        for (; t + 4 <= m; t += 4) {
            int s0 = __shfl(idx, t + 0);
            int s1 = __shfl(idx, t + 1);
            int s2 = __shfl(idx, t + 2);
            int s3 = __shfl(idx, t + 3);
            a0 += h[(size_t)s0 * 64 + lane];
            a1 += h[(size_t)s1 * 64 + lane];
            a2 += h[(size_t)s2 * 64 + lane];
            a3 += h[(size_t)s3 * 64 + lane];
        }
        for (; t < m; ++t) {
            int s = __shfl(idx, t);
            a0 += h[(size_t)s * 64 + lane];
        }
        float sum = (a0 + a1) + (a2 + a3);
        agg[(size_t)task * 64 + lane] = sum / (float)max(d, 1);
    }
}

// Add overflowed edges' contribution (already-divided) into agg. Usually 0 work.
__global__ __launch_bounds__(256) void ovf_fix(
    const int2* __restrict__ ovf, const int* __restrict__ ovf_cnt,
    const int* __restrict__ deg, const float* __restrict__ h,
    float* __restrict__ agg)
{
    int cnt = min(*ovf_cnt, OVF_CAP);
    int total = cnt * 64;
    int stride = gridDim.x * blockDim.x;
    for (int t = blockIdx.x * blockDim.x + threadIdx.x; t < total; t += stride) {
        int e = t >> 6, f = t & 63;
        int2 v = ovf[e];
        float val = h[(size_t)v.y * 64 + f] / (float)max(deg[v.x], 1);
        atomicAdd(&agg[(size_t)v.x * 64 + f], val);
    }
}

// hout[i,:] = relu( mean0[i,:]@Wl0 + mean1[i,:]@Wl1 + h[i,:]@(Wr0+Wr1) + (b0+b1) )
// Safe to run in-place (hout == h): only node i's own h row is read for node i.
__global__ __launch_bounds__(256) void layer_gemm(
    const float* __restrict__ agg0, const float* __restrict__ agg1,
    const float* __restrict__ h,
    const float* __restrict__ Wl0, const float* __restrict__ Wl1,
    const float* __restrict__ Wr0, const float* __restrict__ Wr1,
    const float* __restrict__ b0, const float* __restrict__ b1,
    float* __restrict__ hout)
{
    __shared__ float Wc[192 * 64];   // 0-63: Wl0, 64-127: Wl1, 128-191: Wr0+Wr1
    __shared__ float bias[64];
    __shared__ float rows[4][192];

    int tid = threadIdx.x;
    for (int i = tid; i < 4096; i += 256) {
        Wc[i]        = Wl0[i];
        Wc[4096 + i] = Wl1[i];
        Wc[8192 + i] = Wr0[i] + Wr1[i];
    }
    if (tid < 64) bias[tid] = b0[tid] + b1[tid];

    int j = tid & 63;
    int nl = tid >> 6;

    for (int base = blockIdx.x * 4; base < NN; base += gridDim.x * 4) {
        __syncthreads();
        // Stage 4 nodes x 192 features as float4s (192 float4 loads, tid<192)
        if (tid < 192) {
            int n = tid / 48, kq = tid % 48;
            int node = base + n;
            float4 v = make_float4(0.f, 0.f, 0.f, 0.f);
            if (node < NN) {
                if (kq < 16)      v = *(const float4*)&agg0[(size_t)node * 64 + kq * 4];
                else if (kq < 32) v = *(const float4*)&agg1[(size_t)node * 64 + (kq - 16) * 4];
                else              v = *(const float4*)&h[(size_t)node * 64 + (kq - 32) * 4];
            }
            *(float4*)&rows[n][kq * 4] = v;
        }
        __syncthreads();

        int node = base + nl;
        if (node < NN) {
            float acc = bias[j];
            #pragma unroll
            for (int k = 0; k < 192; k += 4) {
                float4 rv = *(const float4*)&rows[nl][k];
                acc = fmaf(rv.x, Wc[(k + 0) * 64 + j], acc);
                acc = fmaf(rv.y, Wc[(k + 1) * 64 + j], acc);
                acc = fmaf(rv.z, Wc[(k + 2) * 64 + j], acc);
                acc = fmaf(rv.w, Wc[(k + 3) * 64 + j], acc);
            }
            hout[(size_t)node * 64 + j] = fmaxf(acc, 0.0f);
        }
    }
}

// out[i,:32] = h[i,:64] @ W + b
__global__ __launch_bounds__(256) void final_gemm(
    const float* __restrict__ h, const float* __restrict__ W,
    const float* __restrict__ b, float* __restrict__ out)
{
    __shared__ float Ws[64 * 32];
    __shared__ float bs[32];
    __shared__ float rows[8][64];

    int tid = threadIdx.x;
    for (int i = tid; i < 2048; i += 256) Ws[i] = W[i];
    if (tid < 32) bs[tid] = b[tid];

    int j = tid & 31;
    int nl = tid >> 5;

    for (int base = blockIdx.x * 8; base < NN; base += gridDim.x * 8) {
        __syncthreads();
        if (tid < 128) {
            int n = tid >> 4, kq = tid & 15;
            int node = base + n;
            float4 v = make_float4(0.f, 0.f, 0.f, 0.f);
            if (node < NN) v = *(const float4*)&h[(size_t)node * 64 + kq * 4];
            *(float4*)&rows[n][kq * 4] = v;
        }
        __syncthreads();

        int node = base + nl;
        if (node < NN) {
            float acc = bs[j];
            #pragma unroll
            for (int k = 0; k < 64; k += 4) {
                float4 rv = *(const float4*)&rows[nl][k];
                acc = fmaf(rv.x, Ws[(k + 0) * 32 + j], acc);
                acc = fmaf(rv.y, Ws[(k + 1) * 32 + j], acc);
                acc = fmaf(rv.z, Ws[(k + 2) * 32 + j], acc);
                acc = fmaf(rv.w, Ws[(k + 3) * 32 + j], acc);
            }
            out[(size_t)node * 32 + j] = acc;
        }
    }
}

extern "C" void kernel_launch(void* const* d_in, const int* in_sizes, int n_in,
                              void* d_out, int out_size, void* d_ws, size_t ws_size,
                              hipStream_t stream)
{
    const float* x    = (const float*)d_in[0];
    const int*   ei0  = (const int*)d_in[1];
    const int*   ei1  = (const int*)d_in[2];
    const float* Wl   = (const float*)d_in[3];   // [2,2,64,64]
    const float* Wr   = (const float*)d_in[4];   // [2,2,64,64]
    const float* bl   = (const float*)d_in[5];   // [2,2,64]
    const float* linW = (const float*)d_in[6];   // [64,32]
    const float* linb = (const float*)d_in[7];   // [32]
    float* out = (float*)d_out;

    int E0 = in_sizes[1] / 2;
    int E1 = in_sizes[2] / 2;

    // Workspace layout (~51.6 MB):
    // [deg 2*NN int | ovf_cnt 4 int | ovf OVF_CAP int2 | bins 2*NN*CAP int |
    //  agg 2*NN*64 f | h1 NN*64 f]
    int*  deg     = (int*)d_ws;
    int*  ovf_cnt = deg + 2 * NN;
    int2* ovf     = (int2*)(ovf_cnt + 4);
    int*  bins    = (int*)(ovf + OVF_CAP);
    float* agg    = (float*)(bins + (size_t)2 * NN * CAP);
    float* agg0   = agg;
    float* agg1   = agg + (size_t)NN * 64;
    float* h1     = agg + (size_t)2 * NN * 64;

    dim3 blk(256);

    // Build bins once (shared by both layers: edge lists don't change)
    (void)hipMemsetAsync(deg, 0, (2 * NN + 4) * sizeof(int), stream);
    bin_fill<<<2048, blk, 0, stream>>>(ei0, E0, ei1, E1, deg, bins, ovf, ovf_cnt);

    // ---- Layer 0 (input x) ----
    aggregate<<<4096, blk, 0, stream>>>(bins, deg, x, agg);
    ovf_fix<<<64, blk, 0, stream>>>(ovf, ovf_cnt, deg, x, agg);
    layer_gemm<<<768, blk, 0, stream>>>(agg0, agg1, x,
        Wl + 0, Wl + 4096, Wr + 0, Wr + 4096, bl + 0, bl + 64, h1);

    // ---- Layer 1 (input h1, output in-place h1) ----
    aggregate<<<4096, blk, 0, stream>>>(bins, deg, h1, agg);
    ovf_fix<<<64, blk, 0, stream>>>(ovf, ovf_cnt, deg, h1, agg);
    layer_gemm<<<768, blk, 0, stream>>>(agg0, agg1, h1,
        Wl + 8192, Wl + 12288, Wr + 8192, Wr + 12288, bl + 128, bl + 192, h1);

    // ---- Final projection ----
    final_gemm<<<768, blk, 0, stream>>>(h1, linW, linb, out);
}

// Round 4
// 342.642 us; speedup vs baseline: 2.9094x; 1.3599x over previous
//
#include <hip/hip_runtime.h>

#define NN 50000
#define CAP 32          // per-node bin capacity; overflow handled correctly
#define OVF_CAP 4096

// Sharded bin fill: shard class = (node & 7); block group s = blockIdx%8 scans
// the whole edge list keeping only shard-s edges. With round-robin block->XCD
// placement, each node's bin lines are written by ONE XCD -> its L2 merges the
// ~16 partial 4B stores into full lines (R3: 97MB HBM WRITE = unmerged lines).
// Correctness does not depend on the actual XCD mapping.
__global__ __launch_bounds__(256) void bin_fill(
    const int* __restrict__ ei0, int E0,
    const int* __restrict__ ei1, int E1,
    int* __restrict__ deg,       // [2*NN]
    int* __restrict__ bins,      // [2*NN][CAP]
    int2* __restrict__ ovf, int* __restrict__ ovf_cnt)
{
    int shard = blockIdx.x & 7;
    int lblk  = blockIdx.x >> 3;
    int lgrid = gridDim.x >> 3;
    int total = E0 + E1;
    int stride = lgrid * blockDim.x;
    for (int t = lblk * blockDim.x + threadIdx.x; t < total; t += stride) {
        int node;
        const int* srcp;
        if (t < E0) { node = ei0[E0 + t]; srcp = ei0 + t; }
        else        { int u = t - E0; node = NN + ei1[E1 + u]; srcp = ei1 + u; }
        if ((node & 7) == shard) {
            int s = *srcp;                       // only fetch src for kept edges
            int r = atomicAdd(&deg[node], 1);
            if (r < CAP) {
                bins[(size_t)node * CAP + r] = s;
            } else {
                int o = atomicAdd(ovf_cnt, 1);
                if (o < OVF_CAP) ovf[o] = make_int2(node, s);
            }
        }
    }
}

// One wave per (relation,node): coalesced bin read, shfl-broadcast indices,
// 4 independent gather-accumulate chains, write mean.
__global__ __launch_bounds__(256) void aggregate(
    const int* __restrict__ bins, const int* __restrict__ deg,
    const float* __restrict__ h, float* __restrict__ agg)
{
    int lane = threadIdx.x & 63;
    int wid = (blockIdx.x * blockDim.x + threadIdx.x) >> 6;
    int nwaves = (gridDim.x * blockDim.x) >> 6;
    for (int task = wid; task < 2 * NN; task += nwaves) {
        int d = deg[task];
        int m = min(d, CAP);
        int idx = 0;
        if (lane < m) idx = bins[(size_t)task * CAP + lane];
        float a0 = 0.f, a1 = 0.f, a2 = 0.f, a3 = 0.f;
        int t = 0;
        for (; t + 4 <= m; t += 4) {
            int s0 = __shfl(idx, t + 0);
            int s1 = __shfl(idx, t + 1);
            int s2 = __shfl(idx, t + 2);
            int s3 = __shfl(idx, t + 3);
            a0 += h[(size_t)s0 * 64 + lane];
            a1 += h[(size_t)s1 * 64 + lane];
            a2 += h[(size_t)s2 * 64 + lane];
            a3 += h[(size_t)s3 * 64 + lane];
        }
        for (; t < m; ++t) {
            int s = __shfl(idx, t);
            a0 += h[(size_t)s * 64 + lane];
        }
        float sum = (a0 + a1) + (a2 + a3);
        agg[(size_t)task * 64 + lane] = sum / (float)max(d, 1);
    }
}

// Add overflowed edges' contribution (already-divided) into agg. Usually 0 work.
__global__ __launch_bounds__(256) void ovf_fix(
    const int2* __restrict__ ovf, const int* __restrict__ ovf_cnt,
    const int* __restrict__ deg, const float* __restrict__ h,
    float* __restrict__ agg)
{
    int cnt = min(*ovf_cnt, OVF_CAP);
    int total = cnt * 64;
    int stride = gridDim.x * blockDim.x;
    for (int t = blockIdx.x * blockDim.x + threadIdx.x; t < total; t += stride) {
        int e = t >> 6, f = t & 63;
        int2 v = ovf[e];
        float val = h[(size_t)v.y * 64 + f] / (float)max(deg[v.x], 1);
        atomicAdd(&agg[(size_t)v.x * 64 + f], val);
    }
}

// hout = relu(mean0@Wl0 + mean1@Wl1 + h@(Wr0+Wr1) + (b0+b1))
// Register-tiled: block = 128 nodes x 64 cols, thread = 4 nodes x 8 cols.
// K in 3 chunks of 64 (one per source). Node features staged TRANSPOSED
// (rowsT[k][node]) so inner loop = 3x ds_read_b128 per k (1.5 B LDS/FMA vs
// 8 B/FMA in the R3 version, which was LDS-BW bound at ~70us).
// LDS ~50KB -> 3 blocks/CU. In-place safe (block touches only its own nodes).
#define RST 132   // rowsT row stride: 128 nodes + pad, %4==0 for b128 reads
__global__ __launch_bounds__(256) void layer_gemm(
    const float* __restrict__ agg0, const float* __restrict__ agg1,
    const float* __restrict__ h,
    const float* __restrict__ Wl0, const float* __restrict__ Wl1,
    const float* __restrict__ Wr0, const float* __restrict__ Wr1,
    const float* __restrict__ b0, const float* __restrict__ b1,
    float* __restrict__ hout)
{
    __shared__ float Wch[64 * 64];     // current chunk's 64x64 weight block
    __shared__ float rowsT[64 * RST];  // [k][node] transposed features
    __shared__ float bias[64];

    int tid = threadIdx.x;
    int base = blockIdx.x * 128;
    if (tid < 64) bias[tid] = b0[tid] + b1[tid];

    int j8 = (tid & 7) * 8;        // 8 output cols
    int n4 = (tid >> 3) * 4;       // 4 nodes

    float acc[4][8];
    #pragma unroll
    for (int i = 0; i < 4; i++)
        #pragma unroll
        for (int c = 0; c < 8; c++) acc[i][c] = 0.f;

    for (int chunk = 0; chunk < 3; chunk++) {
        const float* W   = (chunk == 0) ? Wl0  : (chunk == 1) ? Wl1  : Wr0;
        const float* src = (chunk == 0) ? agg0 : (chunk == 1) ? agg1 : h;
        __syncthreads();   // protect LDS reuse from previous chunk's compute
        // stage weights (4096 floats; chunk 2 fuses Wr0+Wr1)
        #pragma unroll
        for (int r = 0; r < 4; r++) {
            int i = tid + 256 * r;                 // float4 index
            float4 w = *(const float4*)&W[i * 4];
            if (chunk == 2) {
                float4 w2 = *(const float4*)&Wr1[i * 4];
                w.x += w2.x; w.y += w2.y; w.z += w2.z; w.w += w2.w;
            }
            *(float4*)&Wch[i * 4] = w;
        }
        // stage 128 node rows, transposed into rowsT[k][node]
        #pragma unroll
        for (int r = 0; r < 8; r++) {
            int i = tid + 256 * r;                 // float4 index, node-major
            int node = i >> 4;
            int k4 = (i & 15) * 4;
            float4 v = make_float4(0.f, 0.f, 0.f, 0.f);
            int g = base + node;
            if (g < NN) v = *(const float4*)&src[(size_t)g * 64 + k4];
            rowsT[(k4 + 0) * RST + node] = v.x;
            rowsT[(k4 + 1) * RST + node] = v.y;
            rowsT[(k4 + 2) * RST + node] = v.z;
            rowsT[(k4 + 3) * RST + node] = v.w;
        }
        __syncthreads();
        #pragma unroll 4
        for (int k = 0; k < 64; k++) {
            float4 wa = *(const float4*)&Wch[k * 64 + j8];
            float4 wb = *(const float4*)&Wch[k * 64 + j8 + 4];
            float4 rv = *(const float4*)&rowsT[k * RST + n4];
            float w[8] = {wa.x, wa.y, wa.z, wa.w, wb.x, wb.y, wb.z, wb.w};
            float rr[4] = {rv.x, rv.y, rv.z, rv.w};
            #pragma unroll
            for (int i = 0; i < 4; i++)
                #pragma unroll
                for (int c = 0; c < 8; c++)
                    acc[i][c] = fmaf(rr[i], w[c], acc[i][c]);
        }
    }

    #pragma unroll
    for (int i = 0; i < 4; i++) {
        int g = base + n4 + i;
        if (g < NN) {
            float4 o1, o2;
            o1.x = fmaxf(acc[i][0] + bias[j8 + 0], 0.f);
            o1.y = fmaxf(acc[i][1] + bias[j8 + 1], 0.f);
            o1.z = fmaxf(acc[i][2] + bias[j8 + 2], 0.f);
            o1.w = fmaxf(acc[i][3] + bias[j8 + 3], 0.f);
            o2.x = fmaxf(acc[i][4] + bias[j8 + 4], 0.f);
            o2.y = fmaxf(acc[i][5] + bias[j8 + 5], 0.f);
            o2.z = fmaxf(acc[i][6] + bias[j8 + 6], 0.f);
            o2.w = fmaxf(acc[i][7] + bias[j8 + 7], 0.f);
            *(float4*)&hout[(size_t)g * 64 + j8]     = o1;
            *(float4*)&hout[(size_t)g * 64 + j8 + 4] = o2;
        }
    }
}

// out[i,:32] = h[i,:64] @ W + b
__global__ __launch_bounds__(256) void final_gemm(
    const float* __restrict__ h, const float* __restrict__ W,
    const float* __restrict__ b, float* __restrict__ out)
{
    __shared__ float Ws[64 * 32];
    __shared__ float bs[32];
    __shared__ float rows[8][64];

    int tid = threadIdx.x;
    for (int i = tid; i < 2048; i += 256) Ws[i] = W[i];
    if (tid < 32) bs[tid] = b[tid];

    int j = tid & 31;
    int nl = tid >> 5;

    for (int base = blockIdx.x * 8; base < NN; base += gridDim.x * 8) {
        __syncthreads();
        if (tid < 128) {
            int n = tid >> 4, kq = tid & 15;
            int node = base + n;
            float4 v = make_float4(0.f, 0.f, 0.f, 0.f);
            if (node < NN) v = *(const float4*)&h[(size_t)node * 64 + kq * 4];
            *(float4*)&rows[n][kq * 4] = v;
        }
        __syncthreads();

        int node = base + nl;
        if (node < NN) {
            float acc = bs[j];
            #pragma unroll
            for (int k = 0; k < 64; k += 4) {
                float4 rv = *(const float4*)&rows[nl][k];
                acc = fmaf(rv.x, Ws[(k + 0) * 32 + j], acc);
                acc = fmaf(rv.y, Ws[(k + 1) * 32 + j], acc);
                acc = fmaf(rv.z, Ws[(k + 2) * 32 + j], acc);
                acc = fmaf(rv.w, Ws[(k + 3) * 32 + j], acc);
            }
            out[(size_t)node * 32 + j] = acc;
        }
    }
}

extern "C" void kernel_launch(void* const* d_in, const int* in_sizes, int n_in,
                              void* d_out, int out_size, void* d_ws, size_t ws_size,
                              hipStream_t stream)
{
    const float* x    = (const float*)d_in[0];
    const int*   ei0  = (const int*)d_in[1];
    const int*   ei1  = (const int*)d_in[2];
    const float* Wl   = (const float*)d_in[3];   // [2,2,64,64]
    const float* Wr   = (const float*)d_in[4];   // [2,2,64,64]
    const float* bl   = (const float*)d_in[5];   // [2,2,64]
    const float* linW = (const float*)d_in[6];   // [64,32]
    const float* linb = (const float*)d_in[7];   // [32]
    float* out = (float*)d_out;

    int E0 = in_sizes[1] / 2;
    int E1 = in_sizes[2] / 2;

    // Workspace layout (~51.6 MB):
    // [deg 2*NN int | ovf_cnt 4 int | ovf OVF_CAP int2 | bins 2*NN*CAP int |
    //  agg 2*NN*64 f | h1 NN*64 f]
    int*  deg     = (int*)d_ws;
    int*  ovf_cnt = deg + 2 * NN;
    int2* ovf     = (int2*)(ovf_cnt + 4);
    int*  bins    = (int*)(ovf + OVF_CAP);
    float* agg    = (float*)(bins + (size_t)2 * NN * CAP);
    float* agg0   = agg;
    float* agg1   = agg + (size_t)NN * 64;
    float* h1     = agg + (size_t)2 * NN * 64;

    dim3 blk(256);
    int ggrid = (NN + 127) / 128;   // 391

    // Build bins once (shared by both layers: edge lists don't change)
    (void)hipMemsetAsync(deg, 0, (2 * NN + 4) * sizeof(int), stream);
    bin_fill<<<2048, blk, 0, stream>>>(ei0, E0, ei1, E1, deg, bins, ovf, ovf_cnt);

    // ---- Layer 0 (input x) ----
    aggregate<<<4096, blk, 0, stream>>>(bins, deg, x, agg);
    ovf_fix<<<64, blk, 0, stream>>>(ovf, ovf_cnt, deg, x, agg);
    layer_gemm<<<ggrid, blk, 0, stream>>>(agg0, agg1, x,
        Wl + 0, Wl + 4096, Wr + 0, Wr + 4096, bl + 0, bl + 64, h1);

    // ---- Layer 1 (input h1, output in-place h1) ----
    aggregate<<<4096, blk, 0, stream>>>(bins, deg, h1, agg);
    ovf_fix<<<64, blk, 0, stream>>>(ovf, ovf_cnt, deg, h1, agg);
    layer_gemm<<<ggrid, blk, 0, stream>>>(agg0, agg1, h1,
        Wl + 8192, Wl + 12288, Wr + 8192, Wr + 12288, bl + 128, bl + 192, h1);

    // ---- Final projection ----
    final_gemm<<<768, blk, 0, stream>>>(h1, linW, linb, out);
}